// Round 1
// baseline (6765.758 us; speedup 1.0000x reference)
//
#include <hip/hip_runtime.h>
#include <hip/hip_bf16.h>
#include <math.h>

#define BB 16
#define LL 4096
#define DD 1024
#define OD 64
#define NP 2016
#define NC 256
#define VD 64
#define NCHUNK 64
#define LCH (LL / NCHUNK)

__device__ __forceinline__ int triu_idx(int r, int c) {
  // np.triu_indices(64, k=1), row-major: idx = sum_{t<r}(63-t) + (c-r-1)
  return r * 63 - (r * (r - 1)) / 2 + (c - r - 1);
}

// ---------------- Kernel 1a: partial sums over L chunks ----------------
__global__ void k_partial(const float* __restrict__ x, float* __restrict__ partial) {
  const int b = blockIdx.y, ch = blockIdx.x, tid = threadIdx.x;
  const float4* xp = (const float4*)(x + ((size_t)b * LL + (size_t)ch * LCH) * DD) + tid;
  float4 s = make_float4(0.f, 0.f, 0.f, 0.f);
  #pragma unroll 8
  for (int l = 0; l < LCH; ++l) {
    float4 v = xp[(size_t)l * (DD / 4)];
    s.x += v.x; s.y += v.y; s.z += v.z; s.w += v.w;
  }
  ((float4*)(partial + ((size_t)(b * NCHUNK + ch)) * DD))[tid] = s;
}

// ---------------- Kernel 1b: finalize mean ----------------
__global__ void k_mean(const float* __restrict__ partial, float* __restrict__ hm) {
  const int b = blockIdx.x, tid = threadIdx.x;
  float4 s = make_float4(0.f, 0.f, 0.f, 0.f);
  for (int c = 0; c < NCHUNK; ++c) {
    float4 v = ((const float4*)(partial + ((size_t)(b * NCHUNK + c)) * DD))[tid];
    s.x += v.x; s.y += v.y; s.z += v.z; s.w += v.w;
  }
  const float inv = 1.0f / (float)LL;
  s.x *= inv; s.y *= inv; s.z *= inv; s.w *= inv;
  ((float4*)(hm + (size_t)b * DD))[tid] = s;
}

// ---------------- Kernel 2a: params = h_mean @ opw.T + opb (wave per param) ----------------
__global__ void k_params(const float* __restrict__ hm, const float* __restrict__ w,
                         const float* __restrict__ bias, float* __restrict__ params) {
  const int wave = threadIdx.x >> 6, lane = threadIdx.x & 63;
  const int p = blockIdx.x * 4 + wave;  // grid = NP/4 = 504
  float acc[BB];
  #pragma unroll
  for (int b = 0; b < BB; ++b) acc[b] = 0.f;
  const float* wr = w + (size_t)p * DD;
  for (int i = 0; i < DD; i += 64) {
    const float wv = wr[i + lane];
    #pragma unroll
    for (int b = 0; b < BB; ++b) acc[b] = fmaf(wv, hm[b * DD + i + lane], acc[b]);
  }
  #pragma unroll
  for (int b = 0; b < BB; ++b) {
    float v = acc[b];
    #pragma unroll
    for (int mk = 32; mk; mk >>= 1) v += __shfl_xor(v, mk, 64);
    if (lane == 0) params[(size_t)b * NP + p] = v + bias[p];
  }
}

// ---------------- Kernel 2b: per-batch omega -> G, VQ path, c vector ----------------
__global__ void k_perb(const float* __restrict__ hm, const float* __restrict__ params,
                       const float* __restrict__ viw, const float* __restrict__ vib,
                       const float* __restrict__ cb,
                       const float* __restrict__ oob, const float* __restrict__ vow,
                       const float* __restrict__ vob,
                       const float* __restrict__ omix_p, const float* __restrict__ vmix_p,
                       float* __restrict__ Gout, float* __restrict__ cvec) {
  const int b = blockIdx.x, tid = threadIdx.x;
  __shared__ float om[OD][OD + 1];
  __shared__ float om2[OD][OD + 1];
  __shared__ float vqi[VD];
  __shared__ float sc[NC];
  __shared__ int si[NC];
  __shared__ float cd[VD];
  __shared__ float nv_s;
  const float* par = params + (size_t)b * NP;

  for (int e2 = tid; e2 < OD * OD; e2 += 256) {
    int i = e2 >> 6, j = e2 & 63;
    float v = 0.f;
    if (i < j) v = par[triu_idx(i, j)];
    else if (i > j) v = -par[triu_idx(j, i)];
    om[i][j] = v;
  }
  __syncthreads();
  for (int e2 = tid; e2 < OD * OD; e2 += 256) {
    int i = e2 >> 6, j = e2 & 63;
    float s = 0.f;
    #pragma unroll 8
    for (int k = 0; k < OD; ++k) s = fmaf(om[i][k], om[k][j], s);
    om2[i][j] = s;
  }
  __syncthreads();
  for (int e2 = tid; e2 < OD * OD; e2 += 256) {
    int i = e2 >> 6, j = e2 & 63;
    float s3 = 0.f;
    #pragma unroll 8
    for (int k = 0; k < OD; ++k) s3 = fmaf(om2[i][k], om[k][j], s3);
    float gv = om[i][j] + 0.5f * om2[i][j] + (1.f / 6.f) * s3 + (i == j ? 1.f : 0.f);
    Gout[(size_t)b * OD * OD + e2] = gv;
  }
  // VQ input: 64-dim projection of h_mean
  if (tid < VD) {
    float a = vib[tid];
    const float* wr = viw + (size_t)tid * DD;
    const float* h = hm + (size_t)b * DD;
    #pragma unroll 8
    for (int k = 0; k < DD; ++k) a = fmaf(wr[k], h[k], a);
    vqi[tid] = a;
  }
  __syncthreads();
  if (tid == 0) {
    float s = 0.f;
    for (int k = 0; k < VD; ++k) s += vqi[k] * vqi[k];
    nv_s = fmaxf(sqrtf(s), 1e-12f);
  }
  __syncthreads();
  {
    const float* cr = cb + (size_t)tid * VD;
    float dot = 0.f, ssq = 0.f;
    #pragma unroll 8
    for (int k = 0; k < VD; ++k) { float cvv = cr[k]; dot = fmaf(cvv, vqi[k], dot); ssq = fmaf(cvv, cvv, ssq); }
    float ncn = fmaxf(sqrtf(ssq), 1e-12f);
    sc[tid] = dot / (nv_s * ncn);
    si[tid] = tid;
  }
  __syncthreads();
  for (int s = 128; s > 0; s >>= 1) {
    if (tid < s) {
      float a = sc[tid], b2 = sc[tid + s];
      int ia = si[tid], ib = si[tid + s];
      if (b2 > a || (b2 == a && ib < ia)) { sc[tid] = b2; si[tid] = ib; }
    }
    __syncthreads();
  }
  const int best = si[0];
  if (tid < VD) cd[tid] = cb[(size_t)best * VD + tid];
  __syncthreads();
  const float omix = omix_p[0], vmix = vmix_p[0];
  for (int e = tid; e < DD; e += 256) {
    float a = vob[e];
    const float* wr = vow + (size_t)e * VD;
    #pragma unroll 8
    for (int k = 0; k < VD; ++k) a = fmaf(cd[k], wr[k], a);
    cvec[(size_t)b * DD + e] = fmaf(omix, oob[e], vmix * a);
  }
}

// ---------------- Kernel 2c: M = omix * G @ oow.T  (64 x 1024 per batch) ----------------
__global__ void k_M(const float* __restrict__ G, const float* __restrict__ oow,
                    const float* __restrict__ omix_p, float* __restrict__ M) {
  const int b = blockIdx.y, eb = blockIdx.x * 64, tid = threadIdx.x;
  __shared__ float g[OD][OD];
  __shared__ float wl[64][65];
  for (int e2 = tid; e2 < OD * OD; e2 += 256) g[e2 >> 6][e2 & 63] = G[(size_t)b * OD * OD + e2];
  for (int e2 = tid; e2 < 64 * 64; e2 += 256) wl[e2 >> 6][e2 & 63] = oow[(size_t)(eb + (e2 >> 6)) * 64 + (e2 & 63)];
  __syncthreads();
  const float omix = omix_p[0];
  for (int o = tid; o < 4096; o += 256) {
    int d = o >> 6, e = o & 63;
    float s = 0.f;
    #pragma unroll
    for (int k = 0; k < 64; ++k) s = fmaf(g[d][k], wl[e][k], s);
    M[((size_t)b * OD + d) * DD + eb + e] = omix * s;
  }
}

// ---------------- Kernel 3: main pass ----------------
// 1024 threads = one e-column each; M column (64 floats) in registers.
__global__ __launch_bounds__(1024, 4)
void k_main(const float* __restrict__ x, const float* __restrict__ M,
            const float* __restrict__ cvec, const float* __restrict__ nw,
            float* __restrict__ out) {
  const int b = blockIdx.y;
  const int tbase = blockIdx.x * (LL / 16);  // 256 tokens per block
  const int e = threadIdx.x;
  const int lane = e & 63, wid = e >> 6;
  float m[OD];
  #pragma unroll
  for (int d = 0; d < OD; ++d) m[d] = M[((size_t)b * OD + d) * DD + e];
  const float ce = cvec[(size_t)b * DD + e];
  const float nwe = nw[e];
  __shared__ float xh[8][OD];
  __shared__ float red[8][16];
  const size_t xbase = ((size_t)b * LL + tbase) * DD;

  for (int t0 = 0; t0 < 256; t0 += 8) {
    float xv[8], y[8];
    const float* xp = x + xbase + (size_t)t0 * DD + e;
    #pragma unroll
    for (int t = 0; t < 8; ++t) xv[t] = xp[(size_t)t * DD];
    if (e < OD) {
      #pragma unroll
      for (int t = 0; t < 8; ++t) xh[t][e] = xv[t];
    }
    __syncthreads();
    #pragma unroll
    for (int t = 0; t < 8; ++t) {
      const float4* xh4 = (const float4*)xh[t];
      float r = 0.f;
      #pragma unroll
      for (int d4 = 0; d4 < 16; ++d4) {
        float4 h = xh4[d4];
        r = fmaf(h.x, m[4 * d4 + 0], r);
        r = fmaf(h.y, m[4 * d4 + 1], r);
        r = fmaf(h.z, m[4 * d4 + 2], r);
        r = fmaf(h.w, m[4 * d4 + 3], r);
      }
      y[t] = xv[t] + r + ce;
    }
    #pragma unroll
    for (int t = 0; t < 8; ++t) {
      float ss = y[t] * y[t];
      #pragma unroll
      for (int mk = 32; mk; mk >>= 1) ss += __shfl_xor(ss, mk, 64);
      if (lane == 0) red[t][wid] = ss;
    }
    __syncthreads();
    float* op = out + xbase + (size_t)t0 * DD + e;
    #pragma unroll
    for (int t = 0; t < 8; ++t) {
      float ms = 0.f;
      #pragma unroll
      for (int wv = 0; wv < 16; ++wv) ms += red[t][wv];
      const float scale = rsqrtf(ms * (1.f / (float)DD) + 1e-6f);
      op[(size_t)t * DD] = y[t] * scale * nwe;
    }
    __syncthreads();
  }
}

extern "C" void kernel_launch(void* const* d_in, const int* in_sizes, int n_in,
                              void* d_out, int out_size, void* d_ws, size_t ws_size,
                              hipStream_t stream) {
  (void)in_sizes; (void)n_in; (void)out_size; (void)ws_size;
  const float* x    = (const float*)d_in[0];
  const float* opw  = (const float*)d_in[1];
  const float* opb  = (const float*)d_in[2];
  const float* oow  = (const float*)d_in[3];
  const float* oob  = (const float*)d_in[4];
  const float* viw  = (const float*)d_in[5];
  const float* vib  = (const float*)d_in[6];
  const float* vow  = (const float*)d_in[7];
  const float* vob  = (const float*)d_in[8];
  const float* cb   = (const float*)d_in[9];
  const float* omix = (const float*)d_in[10];
  const float* vmix = (const float*)d_in[11];
  const float* nw   = (const float*)d_in[12];
  float* out = (float*)d_out;

  float* ws      = (float*)d_ws;
  float* partial = ws;                 // 16*64*1024 = 1048576
  float* hm      = ws + 1048576;       // 16384
  float* params  = ws + 1064960;       // 32256
  float* G       = ws + 1097216;       // 65536
  float* M       = ws + 1162752;       // 1048576
  float* cvec    = ws + 2211328;       // 16384  (total ~8.9 MB)

  k_partial<<<dim3(NCHUNK, BB), 256, 0, stream>>>(x, partial);
  k_mean<<<BB, 256, 0, stream>>>(partial, hm);
  k_params<<<NP / 4, 256, 0, stream>>>(hm, opw, opb, params);
  k_perb<<<BB, 256, 0, stream>>>(hm, params, viw, vib, cb, oob, vow, vob, omix, vmix, G, cvec);
  k_M<<<dim3(16, BB), 256, 0, stream>>>(G, oow, omix, M);
  k_main<<<dim3(16, BB), 1024, 0, stream>>>(x, M, cvec, nw, out);
}

// Round 2
// 6760.134 us; speedup vs baseline: 1.0008x; 1.0008x over previous
//
#include <hip/hip_runtime.h>
#include <hip/hip_bf16.h>
#include <math.h>

#define BB 16
#define LL 4096
#define DD 1024
#define OD 64
#define NP 2016
#define NC 256
#define VD 64
#define NCHUNK 64
#define LCH (LL / NCHUNK)

__device__ __forceinline__ int triu_idx(int r, int c) {
  // np.triu_indices(64, k=1), row-major: idx = sum_{t<r}(63-t) + (c-r-1)
  return r * 63 - (r * (r - 1)) / 2 + (c - r - 1);
}

// ---------------- Kernel 1a: partial sums over L chunks ----------------
__global__ void k_partial(const float* __restrict__ x, float* __restrict__ partial) {
  const int b = blockIdx.y, ch = blockIdx.x, tid = threadIdx.x;
  const float4* xp = (const float4*)(x + ((size_t)b * LL + (size_t)ch * LCH) * DD) + tid;
  float4 s = make_float4(0.f, 0.f, 0.f, 0.f);
  #pragma unroll 8
  for (int l = 0; l < LCH; ++l) {
    float4 v = xp[(size_t)l * (DD / 4)];
    s.x += v.x; s.y += v.y; s.z += v.z; s.w += v.w;
  }
  ((float4*)(partial + ((size_t)(b * NCHUNK + ch)) * DD))[tid] = s;
}

// ---------------- Kernel 1b: finalize mean ----------------
__global__ void k_mean(const float* __restrict__ partial, float* __restrict__ hm) {
  const int b = blockIdx.x, tid = threadIdx.x;
  float4 s = make_float4(0.f, 0.f, 0.f, 0.f);
  for (int c = 0; c < NCHUNK; ++c) {
    float4 v = ((const float4*)(partial + ((size_t)(b * NCHUNK + c)) * DD))[tid];
    s.x += v.x; s.y += v.y; s.z += v.z; s.w += v.w;
  }
  const float inv = 1.0f / (float)LL;
  s.x *= inv; s.y *= inv; s.z *= inv; s.w *= inv;
  ((float4*)(hm + (size_t)b * DD))[tid] = s;
}

// ---------------- Kernel 2a: params = h_mean @ opw.T + opb (wave per param) ----------------
__global__ void k_params(const float* __restrict__ hm, const float* __restrict__ w,
                         const float* __restrict__ bias, float* __restrict__ params) {
  const int wave = threadIdx.x >> 6, lane = threadIdx.x & 63;
  const int p = blockIdx.x * 4 + wave;  // grid = NP/4 = 504
  float acc[BB];
  #pragma unroll
  for (int b = 0; b < BB; ++b) acc[b] = 0.f;
  const float* wr = w + (size_t)p * DD;
  for (int i = 0; i < DD; i += 64) {
    const float wv = wr[i + lane];
    #pragma unroll
    for (int b = 0; b < BB; ++b) acc[b] = fmaf(wv, hm[b * DD + i + lane], acc[b]);
  }
  #pragma unroll
  for (int b = 0; b < BB; ++b) {
    float v = acc[b];
    #pragma unroll
    for (int mk = 32; mk; mk >>= 1) v += __shfl_xor(v, mk, 64);
    if (lane == 0) params[(size_t)b * NP + p] = v + bias[p];
  }
}

// ---------------- Kernel 2b: per-batch omega -> G, VQ path, c vector ----------------
__global__ void k_perb(const float* __restrict__ hm, const float* __restrict__ params,
                       const float* __restrict__ viw, const float* __restrict__ vib,
                       const float* __restrict__ cb,
                       const float* __restrict__ oob, const float* __restrict__ vow,
                       const float* __restrict__ vob,
                       const float* __restrict__ omix_p, const float* __restrict__ vmix_p,
                       float* __restrict__ Gout, float* __restrict__ cvec) {
  const int b = blockIdx.x, tid = threadIdx.x;
  __shared__ float om[OD][OD + 1];
  __shared__ float om2[OD][OD + 1];
  __shared__ float vqi[VD];
  __shared__ float sc[NC];
  __shared__ int si[NC];
  __shared__ float cd[VD];
  __shared__ float nv_s;
  const float* par = params + (size_t)b * NP;

  for (int e2 = tid; e2 < OD * OD; e2 += 256) {
    int i = e2 >> 6, j = e2 & 63;
    float v = 0.f;
    if (i < j) v = par[triu_idx(i, j)];
    else if (i > j) v = -par[triu_idx(j, i)];
    om[i][j] = v;
  }
  __syncthreads();
  for (int e2 = tid; e2 < OD * OD; e2 += 256) {
    int i = e2 >> 6, j = e2 & 63;
    float s = 0.f;
    #pragma unroll 8
    for (int k = 0; k < OD; ++k) s = fmaf(om[i][k], om[k][j], s);
    om2[i][j] = s;
  }
  __syncthreads();
  for (int e2 = tid; e2 < OD * OD; e2 += 256) {
    int i = e2 >> 6, j = e2 & 63;
    float s3 = 0.f;
    #pragma unroll 8
    for (int k = 0; k < OD; ++k) s3 = fmaf(om2[i][k], om[k][j], s3);
    float gv = om[i][j] + 0.5f * om2[i][j] + (1.f / 6.f) * s3 + (i == j ? 1.f : 0.f);
    Gout[(size_t)b * OD * OD + e2] = gv;
  }
  // VQ input: 64-dim projection of h_mean
  if (tid < VD) {
    float a = vib[tid];
    const float* wr = viw + (size_t)tid * DD;
    const float* h = hm + (size_t)b * DD;
    #pragma unroll 8
    for (int k = 0; k < DD; ++k) a = fmaf(wr[k], h[k], a);
    vqi[tid] = a;
  }
  __syncthreads();
  if (tid == 0) {
    float s = 0.f;
    for (int k = 0; k < VD; ++k) s += vqi[k] * vqi[k];
    nv_s = fmaxf(sqrtf(s), 1e-12f);
  }
  __syncthreads();
  {
    const float* cr = cb + (size_t)tid * VD;
    float dot = 0.f, ssq = 0.f;
    #pragma unroll 8
    for (int k = 0; k < VD; ++k) { float cvv = cr[k]; dot = fmaf(cvv, vqi[k], dot); ssq = fmaf(cvv, cvv, ssq); }
    float ncn = fmaxf(sqrtf(ssq), 1e-12f);
    sc[tid] = dot / (nv_s * ncn);
    si[tid] = tid;
  }
  __syncthreads();
  for (int s = 128; s > 0; s >>= 1) {
    if (tid < s) {
      float a = sc[tid], b2 = sc[tid + s];
      int ia = si[tid], ib = si[tid + s];
      if (b2 > a || (b2 == a && ib < ia)) { sc[tid] = b2; si[tid] = ib; }
    }
    __syncthreads();
  }
  const int best = si[0];
  if (tid < VD) cd[tid] = cb[(size_t)best * VD + tid];
  __syncthreads();
  const float omix = omix_p[0], vmix = vmix_p[0];
  for (int e = tid; e < DD; e += 256) {
    float a = vob[e];
    const float* wr = vow + (size_t)e * VD;
    #pragma unroll 8
    for (int k = 0; k < VD; ++k) a = fmaf(cd[k], wr[k], a);
    cvec[(size_t)b * DD + e] = fmaf(omix, oob[e], vmix * a);
  }
}

// ---------------- Kernel 2c: M = omix * G @ oow.T  (64 x 1024 per batch) ----------------
__global__ void k_M(const float* __restrict__ G, const float* __restrict__ oow,
                    const float* __restrict__ omix_p, float* __restrict__ M) {
  const int b = blockIdx.y, eb = blockIdx.x * 64, tid = threadIdx.x;
  __shared__ float g[OD][OD];
  __shared__ float wl[64][65];
  for (int e2 = tid; e2 < OD * OD; e2 += 256) g[e2 >> 6][e2 & 63] = G[(size_t)b * OD * OD + e2];
  for (int e2 = tid; e2 < 64 * 64; e2 += 256) wl[e2 >> 6][e2 & 63] = oow[(size_t)(eb + (e2 >> 6)) * 64 + (e2 & 63)];
  __syncthreads();
  const float omix = omix_p[0];
  for (int o = tid; o < 4096; o += 256) {
    int d = o >> 6, e = o & 63;
    float s = 0.f;
    #pragma unroll
    for (int k = 0; k < 64; ++k) s = fmaf(g[d][k], wl[e][k], s);
    M[((size_t)b * OD + d) * DD + eb + e] = omix * s;
  }
}

// ---------------- Kernel 3: main pass ----------------
// 1024 threads = one e-column each; M column (64 floats) in registers.
// __launch_bounds__(1024, 2): VGPR cap 256 so m[64]+xv[8] stay in registers.
// (Round-1 failure: (1024,4) forced the 64-VGPR bin -> m[] spilled to scratch,
//  19 GB of scratch traffic, 6.6 ms. Do NOT raise the occupancy demand.)
__global__ __launch_bounds__(1024, 2)
void k_main(const float* __restrict__ x, const float* __restrict__ M,
            const float* __restrict__ cvec, const float* __restrict__ nw,
            float* __restrict__ out) {
  const int b = blockIdx.y;
  const int tbase = blockIdx.x * (LL / 16);  // 256 tokens per block
  const int e = threadIdx.x;
  const int lane = e & 63, wid = e >> 6;
  float m[OD];
  #pragma unroll
  for (int d = 0; d < OD; ++d) m[d] = M[((size_t)b * OD + d) * DD + e];
  const float ce = cvec[(size_t)b * DD + e];
  const float nwe = nw[e];
  __shared__ float xh[8][OD];
  __shared__ float red[8][16];
  const size_t xbase = ((size_t)b * LL + tbase) * DD;

  for (int t0 = 0; t0 < 256; t0 += 8) {
    float xv[8];
    const float* xp = x + xbase + (size_t)t0 * DD + e;
    #pragma unroll
    for (int t = 0; t < 8; ++t) xv[t] = xp[(size_t)t * DD];
    if (e < OD) {
      #pragma unroll
      for (int t = 0; t < 8; ++t) xh[t][e] = xv[t];
    }
    __syncthreads();
    #pragma unroll
    for (int t = 0; t < 8; ++t) {
      const float4* xh4 = (const float4*)xh[t];
      float r = 0.f;
      #pragma unroll
      for (int d4 = 0; d4 < 16; ++d4) {
        float4 h = xh4[d4];
        r = fmaf(h.x, m[4 * d4 + 0], r);
        r = fmaf(h.y, m[4 * d4 + 1], r);
        r = fmaf(h.z, m[4 * d4 + 2], r);
        r = fmaf(h.w, m[4 * d4 + 3], r);
      }
      xv[t] = xv[t] + r + ce;  // reuse xv as y to cut live registers
    }
    #pragma unroll
    for (int t = 0; t < 8; ++t) {
      float ss = xv[t] * xv[t];
      #pragma unroll
      for (int mk = 32; mk; mk >>= 1) ss += __shfl_xor(ss, mk, 64);
      if (lane == 0) red[t][wid] = ss;
    }
    __syncthreads();
    float* op = out + xbase + (size_t)t0 * DD + e;
    #pragma unroll
    for (int t = 0; t < 8; ++t) {
      float ms = 0.f;
      #pragma unroll
      for (int wv = 0; wv < 16; ++wv) ms += red[t][wv];
      const float scale = rsqrtf(ms * (1.f / (float)DD) + 1e-6f);
      op[(size_t)t * DD] = xv[t] * scale * nwe;
    }
    __syncthreads();
  }
}

extern "C" void kernel_launch(void* const* d_in, const int* in_sizes, int n_in,
                              void* d_out, int out_size, void* d_ws, size_t ws_size,
                              hipStream_t stream) {
  (void)in_sizes; (void)n_in; (void)out_size; (void)ws_size;
  const float* x    = (const float*)d_in[0];
  const float* opw  = (const float*)d_in[1];
  const float* opb  = (const float*)d_in[2];
  const float* oow  = (const float*)d_in[3];
  const float* oob  = (const float*)d_in[4];
  const float* viw  = (const float*)d_in[5];
  const float* vib  = (const float*)d_in[6];
  const float* vow  = (const float*)d_in[7];
  const float* vob  = (const float*)d_in[8];
  const float* cb   = (const float*)d_in[9];
  const float* omix = (const float*)d_in[10];
  const float* vmix = (const float*)d_in[11];
  const float* nw   = (const float*)d_in[12];
  float* out = (float*)d_out;

  float* ws      = (float*)d_ws;
  float* partial = ws;                 // 16*64*1024 = 1048576
  float* hm      = ws + 1048576;       // 16384
  float* params  = ws + 1064960;       // 32256
  float* G       = ws + 1097216;       // 65536
  float* M       = ws + 1162752;       // 1048576
  float* cvec    = ws + 2211328;       // 16384  (total ~8.9 MB)

  k_partial<<<dim3(NCHUNK, BB), 256, 0, stream>>>(x, partial);
  k_mean<<<BB, 256, 0, stream>>>(partial, hm);
  k_params<<<NP / 4, 256, 0, stream>>>(hm, opw, opb, params);
  k_perb<<<BB, 256, 0, stream>>>(hm, params, viw, vib, cb, oob, vow, vob, omix, vmix, G, cvec);
  k_M<<<dim3(16, BB), 256, 0, stream>>>(G, oow, omix, M);
  k_main<<<dim3(16, BB), 1024, 0, stream>>>(x, M, cvec, nw, out);
}